// Round 1
// baseline (2181.949 us; speedup 1.0000x reference)
//
#include <hip/hip_runtime.h>
#include <hip/hip_bf16.h>
#include <math.h>

// Problem constants (B=2, L=1024, d_model=1024, d_inner=2048)
constexpr int Bb  = 2;
constexpr int Ls  = 1024;
constexpr int DM  = 1024;   // d_model
constexpr int DI  = 2048;   // d_inner
constexpr int DXZ = 4096;   // 2*d_inner
constexpr int DXD = 96;     // dt_rank + 2*d_state
constexpr int DTR = 64;     // dt_rank
constexpr int DST = 16;     // d_state

__device__ __forceinline__ float sigmoidf_(float v) {
    return 1.0f / (1.0f + __expf(-v));
}

// ---------------------------------------------------------------------------
// Generic fp32 GEMM:  C[M,N] = A[M,K] @ W[N,K]^T   (both row-major, K contig)
// 128x128 block tile, 256 threads, 8x8 micro-tile, K-step 16.
// Requires M % 128 == 0, K % 16 == 0. N guarded.
// EPI==1: C = softplus(C + bias[col])
// ---------------------------------------------------------------------------
template <int EPI>
__global__ __launch_bounds__(256) void gemm_nt(
    const float* __restrict__ A, int lda,
    const float* __restrict__ W, int ldw,
    float* __restrict__ C, int ldc,
    int N, int K, const float* __restrict__ bias)
{
    __shared__ float As[16][132];
    __shared__ float Ws[16][132];

    const int tid = threadIdx.x;
    const int tx = tid & 15;
    const int ty = tid >> 4;
    const int bm = blockIdx.y * 128;
    const int bn = blockIdx.x * 128;

    // staging: each thread loads 8 contiguous k-floats for one row of A and W
    const int lr = tid >> 1;         // 0..127
    const int lk = (tid & 1) * 8;    // 0 or 8

    float acc[8][8];
#pragma unroll
    for (int i = 0; i < 8; ++i)
#pragma unroll
        for (int j = 0; j < 8; ++j) acc[i][j] = 0.0f;

    const float* Ap = A + (size_t)(bm + lr) * lda + lk;
    const float* Wp = W + (size_t)(bn + lr) * ldw + lk;
    const bool wok = (bn + lr) < N;
    const float4 f4z = make_float4(0.f, 0.f, 0.f, 0.f);

    for (int k0 = 0; k0 < K; k0 += 16) {
        const float4 av0 = *(const float4*)(Ap + k0);
        const float4 av1 = *(const float4*)(Ap + k0 + 4);
        const float4 wv0 = wok ? *(const float4*)(Wp + k0)     : f4z;
        const float4 wv1 = wok ? *(const float4*)(Wp + k0 + 4) : f4z;

        __syncthreads();   // previous tile fully consumed
        As[lk + 0][lr] = av0.x; As[lk + 1][lr] = av0.y;
        As[lk + 2][lr] = av0.z; As[lk + 3][lr] = av0.w;
        As[lk + 4][lr] = av1.x; As[lk + 5][lr] = av1.y;
        As[lk + 6][lr] = av1.z; As[lk + 7][lr] = av1.w;
        Ws[lk + 0][lr] = wv0.x; Ws[lk + 1][lr] = wv0.y;
        Ws[lk + 2][lr] = wv0.z; Ws[lk + 3][lr] = wv0.w;
        Ws[lk + 4][lr] = wv1.x; Ws[lk + 5][lr] = wv1.y;
        Ws[lk + 6][lr] = wv1.z; Ws[lk + 7][lr] = wv1.w;
        __syncthreads();

#pragma unroll
        for (int k = 0; k < 16; ++k) {
            const float4 a0 = *(const float4*)&As[k][(ty << 2)];
            const float4 a1 = *(const float4*)&As[k][64 + (ty << 2)];
            const float4 b0 = *(const float4*)&Ws[k][(tx << 2)];
            const float4 b1 = *(const float4*)&Ws[k][64 + (tx << 2)];
            const float ar[8] = {a0.x, a0.y, a0.z, a0.w, a1.x, a1.y, a1.z, a1.w};
            const float br[8] = {b0.x, b0.y, b0.z, b0.w, b1.x, b1.y, b1.z, b1.w};
#pragma unroll
            for (int i = 0; i < 8; ++i)
#pragma unroll
                for (int j = 0; j < 8; ++j)
                    acc[i][j] = fmaf(ar[i], br[j], acc[i][j]);
        }
    }

#pragma unroll
    for (int i = 0; i < 8; ++i) {
        const int row = bm + ((i & 4) << 4) + (ty << 2) + (i & 3);
#pragma unroll
        for (int j = 0; j < 8; ++j) {
            const int col = bn + ((j & 4) << 4) + (tx << 2) + (j & 3);
            if (col < N) {
                float v = acc[i][j];
                if (EPI == 1) {
                    v += bias[col];
                    v = (v > 20.f) ? v : log1pf(__expf(v));
                }
                C[(size_t)row * ldc + col] = v;
            }
        }
    }
}

// ---------------------------------------------------------------------------
// Depthwise causal conv (width 4) + bias + SiLU.
// xz layout [B*L][4096]; xc = cols 0..2047.  Output xconv [B*L][2048].
// ---------------------------------------------------------------------------
__global__ __launch_bounds__(256) void conv_silu_kernel(
    const float* __restrict__ xz,
    const float* __restrict__ conv_w,
    const float* __restrict__ conv_b,
    float* __restrict__ xconv)
{
    const int idx = blockIdx.x * 256 + threadIdx.x;   // over B*L*DI
    const int d  = idx & (DI - 1);
    const int bl = idx >> 11;
    const int l  = bl & (Ls - 1);

    const float4 cw = *(const float4*)(conv_w + (d << 2));
    const float w[4] = {cw.x, cw.y, cw.z, cw.w};
    float acc = conv_b[d];
    const float* base = xz + (size_t)bl * DXZ + d;
#pragma unroll
    for (int j = 0; j < 4; ++j) {
        const int ll = l - 3 + j;
        if (ll >= 0) acc += base[(j - 3) * DXZ] * w[j];
    }
    xconv[idx] = acc * sigmoidf_(acc);
}

// ---------------------------------------------------------------------------
// Sequential selective scan over L, fused with y = y + x*D and silu(z) gate.
// One thread per (b,d). dt lives in xz cols 0..2047 (xc region reused),
// z in xz cols 2048..4095. Writes y* in-place over xconv.
// ---------------------------------------------------------------------------
__global__ __launch_bounds__(64) void scan_kernel(
    const float* __restrict__ xz,      // [B*L][4096]: cols 0..2047 = dt, 2048.. = z
    float* __restrict__ xconv,         // in: xconv, out: y* (in-place)
    const float* __restrict__ xdbl,    // [B*L][96]: cols 64..95 = B,C
    const float* __restrict__ A_log,   // [DI][16]
    const float* __restrict__ Dp)      // [DI]
{
    const int b = blockIdx.y;
    const int d = blockIdx.x * 64 + threadIdx.x;

    __shared__ float sBC[32];

    float Anat[DST];
#pragma unroll
    for (int n = 0; n < DST; ++n)
        Anat[n] = -__expf(A_log[(d << 4) + n]);
    const float dpd = Dp[d];

    float h[DST];
#pragma unroll
    for (int n = 0; n < DST; ++n) h[n] = 0.0f;

    const float* xzrow = xz    + (size_t)b * Ls * DXZ;
    float*       xcrow = xconv + (size_t)b * Ls * DI;
    const float* xdrow = xdbl  + (size_t)b * Ls * DXD;

    for (int t = 0; t < Ls; ++t) {
        if (threadIdx.x < 32) sBC[threadIdx.x] = xdrow[t * DXD + DTR + threadIdx.x];
        __syncthreads();

        const float dtv = xzrow[(size_t)t * DXZ + d];
        const float zv  = xzrow[(size_t)t * DXZ + DI + d];
        const float xv  = xcrow[(size_t)t * DI + d];
        const float wdx = dtv * xv;

        float y = 0.0f;
#pragma unroll
        for (int n = 0; n < DST; ++n) {
            const float e = __expf(dtv * Anat[n]);
            h[n] = e * h[n] + wdx * sBC[n];
            y = fmaf(h[n], sBC[16 + n], y);
        }
        const float yd = y + xv * dpd;
        xcrow[(size_t)t * DI + d] = yd * (zv * sigmoidf_(zv));
        __syncthreads();
    }
}

// ---------------------------------------------------------------------------
extern "C" void kernel_launch(void* const* d_in, const int* in_sizes, int n_in,
                              void* d_out, int out_size, void* d_ws, size_t ws_size,
                              hipStream_t stream)
{
    const float* x      = (const float*)d_in[0];
    const float* W_in   = (const float*)d_in[1];
    const float* conv_w = (const float*)d_in[2];
    const float* conv_b = (const float*)d_in[3];
    const float* W_x    = (const float*)d_in[4];
    const float* W_dt   = (const float*)d_in[5];
    const float* b_dt   = (const float*)d_in[6];
    const float* A_log  = (const float*)d_in[7];
    const float* Dp     = (const float*)d_in[8];
    const float* W_out  = (const float*)d_in[9];
    float* out = (float*)d_out;

    float* ws    = (float*)d_ws;
    float* xz    = ws;                                  // [2048][4096]  32 MB
    float* xconv = xz    + (size_t)Bb * Ls * DXZ;       // [2048][2048]  16 MB
    float* xdbl  = xconv + (size_t)Bb * Ls * DI;        // [2048][96]   0.75 MB

    const int M = Bb * Ls;  // 2048
    const dim3 blk(256);

    // 1) xz = x @ W_in^T            M=2048 N=4096 K=1024
    gemm_nt<0><<<dim3(DXZ / 128, M / 128), blk, 0, stream>>>(
        x, DM, W_in, DM, xz, DXZ, DXZ, DM, nullptr);

    // 2) depthwise causal conv + silu -> xconv
    conv_silu_kernel<<<dim3((M * DI) / 256), blk, 0, stream>>>(
        xz, conv_w, conv_b, xconv);

    // 3) x_dbl = xconv @ W_x^T      M=2048 N=96 K=2048
    gemm_nt<0><<<dim3(1, M / 128), blk, 0, stream>>>(
        xconv, DI, W_x, DI, xdbl, DXD, DXD, DI, nullptr);

    // 4) dt = softplus(x_dbl[:, :64] @ W_dt^T + b_dt)  -> xz cols 0..2047
    gemm_nt<1><<<dim3(DI / 128, M / 128), blk, 0, stream>>>(
        xdbl, DXD, W_dt, DTR, xz, DXZ, DI, DTR, b_dt);

    // 5) selective scan (+ x*D, silu(z) gate) -> y* in-place over xconv
    scan_kernel<<<dim3(DI / 64, Bb), dim3(64), 0, stream>>>(
        xz, xconv, xdbl, A_log, Dp);

    // 6) out = y* @ W_out^T         M=2048 N=1024 K=2048
    gemm_nt<0><<<dim3(DM / 128, M / 128), blk, 0, stream>>>(
        xconv, DI, W_out, DI, out, DM, DM, DI, nullptr);
}

// Round 4
// 942.218 us; speedup vs baseline: 2.3158x; 2.3158x over previous
//
#include <hip/hip_runtime.h>
#include <hip/hip_bf16.h>
#include <math.h>

// Problem constants (B=2, L=1024, d_model=1024, d_inner=2048)
constexpr int Bb  = 2;
constexpr int Ls  = 1024;
constexpr int DM  = 1024;   // d_model
constexpr int DI  = 2048;   // d_inner
constexpr int DXZ = 4096;   // 2*d_inner
constexpr int DXD = 96;     // dt_rank + 2*d_state
constexpr int DTR = 64;     // dt_rank
constexpr int DST = 16;     // d_state

typedef __attribute__((ext_vector_type(8))) short bf16x8;
typedef __attribute__((ext_vector_type(4))) float f32x4;

__device__ __forceinline__ float sigmoidf_(float v) {
    return 1.0f / (1.0f + __expf(-v));
}

// pack two fp32 -> one dword of 2x bf16 (RTNE)
__device__ __forceinline__ int pk_bf16(float lo, float hi) {
    unsigned int ul = __float_as_uint(lo);
    ul += 0x7fffu + ((ul >> 16) & 1u);
    unsigned int uh = __float_as_uint(hi);
    uh += 0x7fffu + ((uh >> 16) & 1u);
    return (int)((ul >> 16) | (uh & 0xffff0000u));
}

// XOR-swizzled LDS chunk address: tile is [128 rows][4 chunks of 8 bf16].
// chunk idx = (row*4+c) ^ (row&7) — bijective (bits>=3 of x unchanged;
// bit2,1,0 recoverable). Frag reads (16 consecutive rows, fixed chunk)
// spread across 8 bank-quads -> ~2-way (free per m136).
__device__ __forceinline__ int swz(int row, int chunk) {
    return (((row << 2) + chunk) ^ (row & 7)) << 3;
}

// ---------------------------------------------------------------------------
// bf16 MFMA GEMM with fp32 inputs (in-register convert during staging):
// C[M,N] = A[M,K] @ W[N,K]^T, both fp32 row-major K-contig.
// 128x128 tile, 4 waves (2x2 of 64x64), BK=32. M%128==0, N%128==0, K%32==0.
// ---------------------------------------------------------------------------
__global__ __launch_bounds__(256) void gemm_bf16_f32in(
    const float* __restrict__ A, int lda,
    const float* __restrict__ W, int ldw,
    float* __restrict__ C, int ldc, int K)
{
    __shared__ __align__(16) unsigned short As[128 * 32];
    __shared__ __align__(16) unsigned short Ws[128 * 32];

    const int tid  = threadIdx.x;
    const int lane = tid & 63;
    const int wave = tid >> 6;
    const int bm = blockIdx.y * 128;
    const int bn = blockIdx.x * 128;

    // staging: thread t covers row (t>>1), bf16 chunks (t&1)*2 and +1 (16 k's)
    const int srow = tid >> 1;
    const int cb   = (tid & 1) * 2;
    const float* Ag = A + (size_t)(bm + srow) * lda + cb * 8;
    const float* Wg = W + (size_t)(bn + srow) * ldw + cb * 8;
    const int ia0 = swz(srow, cb);
    const int ia1 = swz(srow, cb + 1);

    const int wr = (wave >> 1) * 64;
    const int wc = (wave & 1) * 64;
    const int fr = lane & 15;
    const int fq = lane >> 4;

    f32x4 acc[4][4];
#pragma unroll
    for (int m = 0; m < 4; ++m)
#pragma unroll
        for (int n = 0; n < 4; ++n) acc[m][n] = (f32x4){0.f, 0.f, 0.f, 0.f};

    for (int k0 = 0; k0 < K; k0 += 32) {
        const float4 a0 = *(const float4*)(Ag + k0);
        const float4 a1 = *(const float4*)(Ag + k0 + 4);
        const float4 a2 = *(const float4*)(Ag + k0 + 8);
        const float4 a3 = *(const float4*)(Ag + k0 + 12);
        const float4 w0 = *(const float4*)(Wg + k0);
        const float4 w1 = *(const float4*)(Wg + k0 + 4);
        const float4 w2 = *(const float4*)(Wg + k0 + 8);
        const float4 w3 = *(const float4*)(Wg + k0 + 12);

        __syncthreads();   // all waves done reading previous tile
        {
            const int4 pa0 = {pk_bf16(a0.x, a0.y), pk_bf16(a0.z, a0.w),
                              pk_bf16(a1.x, a1.y), pk_bf16(a1.z, a1.w)};
            const int4 pa1 = {pk_bf16(a2.x, a2.y), pk_bf16(a2.z, a2.w),
                              pk_bf16(a3.x, a3.y), pk_bf16(a3.z, a3.w)};
            const int4 pw0 = {pk_bf16(w0.x, w0.y), pk_bf16(w0.z, w0.w),
                              pk_bf16(w1.x, w1.y), pk_bf16(w1.z, w1.w)};
            const int4 pw1 = {pk_bf16(w2.x, w2.y), pk_bf16(w2.z, w2.w),
                              pk_bf16(w3.x, w3.y), pk_bf16(w3.z, w3.w)};
            *(int4*)(As + ia0) = pa0;
            *(int4*)(As + ia1) = pa1;
            *(int4*)(Ws + ia0) = pw0;
            *(int4*)(Ws + ia1) = pw1;
        }
        __syncthreads();   // staged tile visible

        bf16x8 af[4], bfv[4];
#pragma unroll
        for (int m = 0; m < 4; ++m)
            af[m] = *(const bf16x8*)(As + swz(wr + m * 16 + fr, fq));
#pragma unroll
        for (int n = 0; n < 4; ++n)
            bfv[n] = *(const bf16x8*)(Ws + swz(wc + n * 16 + fr, fq));
#pragma unroll
        for (int m = 0; m < 4; ++m)
#pragma unroll
            for (int n = 0; n < 4; ++n)
                acc[m][n] = __builtin_amdgcn_mfma_f32_16x16x32_bf16(
                    af[m], bfv[n], acc[m][n], 0, 0, 0);
    }

#pragma unroll
    for (int m = 0; m < 4; ++m)
#pragma unroll
        for (int n = 0; n < 4; ++n) {
            const int col = bn + wc + n * 16 + fr;
#pragma unroll
            for (int j = 0; j < 4; ++j) {
                const int row = bm + wr + m * 16 + fq * 4 + j;
                C[(size_t)row * ldc + col] = acc[m][n][j];
            }
        }
}

// ---------------------------------------------------------------------------
// Generic fp32 GEMM (small GEMMs): C[M,N] = A[M,K] @ W[N,K]^T.
// 128x128 tile. EPI==1: softplus(C + bias[col]).
// Split-K via blockIdx.z: A += z*za, W += z*zw, C += z*zc
// (pass K = per-chunk length).
// ---------------------------------------------------------------------------
template <int EPI>
__global__ __launch_bounds__(256) void gemm_nt(
    const float* __restrict__ A, int lda,
    const float* __restrict__ W, int ldw,
    float* __restrict__ C, int ldc,
    int N, int K, const float* __restrict__ bias, int za, int zw, int zc)
{
    A += (size_t)blockIdx.z * za;
    W += (size_t)blockIdx.z * zw;   // <-- round-3 bug: this offset was missing
    C += (size_t)blockIdx.z * zc;

    __shared__ float Asl[16][132];
    __shared__ float Wsl[16][132];

    const int tid = threadIdx.x;
    const int tx = tid & 15;
    const int ty = tid >> 4;
    const int bm = blockIdx.y * 128;
    const int bn = blockIdx.x * 128;

    const int lr = tid >> 1;
    const int lk = (tid & 1) * 8;

    float acc[8][8];
#pragma unroll
    for (int i = 0; i < 8; ++i)
#pragma unroll
        for (int j = 0; j < 8; ++j) acc[i][j] = 0.0f;

    const float* Ap = A + (size_t)(bm + lr) * lda + lk;
    const float* Wp = W + (size_t)(bn + lr) * ldw + lk;
    const bool wok = (bn + lr) < N;
    const float4 f4z = make_float4(0.f, 0.f, 0.f, 0.f);

    for (int k0 = 0; k0 < K; k0 += 16) {
        const float4 av0 = *(const float4*)(Ap + k0);
        const float4 av1 = *(const float4*)(Ap + k0 + 4);
        const float4 wv0 = wok ? *(const float4*)(Wp + k0)     : f4z;
        const float4 wv1 = wok ? *(const float4*)(Wp + k0 + 4) : f4z;

        __syncthreads();
        Asl[lk + 0][lr] = av0.x; Asl[lk + 1][lr] = av0.y;
        Asl[lk + 2][lr] = av0.z; Asl[lk + 3][lr] = av0.w;
        Asl[lk + 4][lr] = av1.x; Asl[lk + 5][lr] = av1.y;
        Asl[lk + 6][lr] = av1.z; Asl[lk + 7][lr] = av1.w;
        Wsl[lk + 0][lr] = wv0.x; Wsl[lk + 1][lr] = wv0.y;
        Wsl[lk + 2][lr] = wv0.z; Wsl[lk + 3][lr] = wv0.w;
        Wsl[lk + 4][lr] = wv1.x; Wsl[lk + 5][lr] = wv1.y;
        Wsl[lk + 6][lr] = wv1.z; Wsl[lk + 7][lr] = wv1.w;
        __syncthreads();

#pragma unroll
        for (int k = 0; k < 16; ++k) {
            const float4 a0 = *(const float4*)&Asl[k][(ty << 2)];
            const float4 a1 = *(const float4*)&Asl[k][64 + (ty << 2)];
            const float4 b0 = *(const float4*)&Wsl[k][(tx << 2)];
            const float4 b1 = *(const float4*)&Wsl[k][64 + (tx << 2)];
            const float ar[8] = {a0.x, a0.y, a0.z, a0.w, a1.x, a1.y, a1.z, a1.w};
            const float br[8] = {b0.x, b0.y, b0.z, b0.w, b1.x, b1.y, b1.z, b1.w};
#pragma unroll
            for (int i = 0; i < 8; ++i)
#pragma unroll
                for (int j = 0; j < 8; ++j)
                    acc[i][j] = fmaf(ar[i], br[j], acc[i][j]);
        }
    }

#pragma unroll
    for (int i = 0; i < 8; ++i) {
        const int row = bm + ((i & 4) << 4) + (ty << 2) + (i & 3);
#pragma unroll
        for (int j = 0; j < 8; ++j) {
            const int col = bn + ((j & 4) << 4) + (tx << 2) + (j & 3);
            if (col < N) {
                float v = acc[i][j];
                if (EPI == 1) {
                    v += bias[col];
                    v = (v > 20.f) ? v : log1pf(__expf(v));
                }
                C[(size_t)row * ldc + col] = v;
            }
        }
    }
}

// ---------------------------------------------------------------------------
// Reduce split-K partials: xdbl[m][j] = sum_kc part[m*DXZ + kc*96 + j]
// ---------------------------------------------------------------------------
__global__ __launch_bounds__(256) void reduce_xdbl_kernel(
    const float* __restrict__ part, float* __restrict__ xdbl)
{
    const int idx = blockIdx.x * 256 + threadIdx.x;   // over 2048*96
    if (idx >= Bb * Ls * DXD) return;
    const int m = idx / DXD;
    const int j = idx - m * DXD;
    const float* p = part + (size_t)m * DXZ + j;
    float s = 0.0f;
#pragma unroll
    for (int kc = 0; kc < 8; ++kc) s += p[kc * DXD];
    xdbl[idx] = s;
}

// ---------------------------------------------------------------------------
// Depthwise causal conv (width 4) + bias + SiLU.
// ---------------------------------------------------------------------------
__global__ __launch_bounds__(256) void conv_silu_kernel(
    const float* __restrict__ xz,
    const float* __restrict__ conv_w,
    const float* __restrict__ conv_b,
    float* __restrict__ xconv)
{
    const int idx = blockIdx.x * 256 + threadIdx.x;   // over B*L*DI
    const int d  = idx & (DI - 1);
    const int bl = idx >> 11;
    const int l  = bl & (Ls - 1);

    const float4 cw = *(const float4*)(conv_w + (d << 2));
    const float w[4] = {cw.x, cw.y, cw.z, cw.w};
    float acc = conv_b[d];
    const float* base = xz + (size_t)bl * DXZ + d;
#pragma unroll
    for (int j = 0; j < 4; ++j) {
        const int ll = l - 3 + j;
        if (ll >= 0) acc += base[(j - 3) * DXZ] * w[j];
    }
    xconv[idx] = acc * sigmoidf_(acc);
}

// ---------------------------------------------------------------------------
// Parallel selective scan: one lane per (b,d,n). 16-lane groups reduce
// y = sum_n h*C via shfl_xor. Zero barriers; 8-deep register prefetch.
// Fuses +x*D and silu(z) gate; writes y* fp32 in-place over xconv.
// ---------------------------------------------------------------------------
__global__ __launch_bounds__(256) void scan_kernel(
    const float* __restrict__ xz,      // cols 0..2047 = dt, 2048.. = z
    float* __restrict__ xconv,         // in: x (silu conv); out: y*
    const float* __restrict__ xdbl,    // cols 64..95 = B,C
    const float* __restrict__ A_log,   // [DI][16]
    const float* __restrict__ Dp)      // [DI]
{
    const int b    = blockIdx.y;
    const int tid  = threadIdx.x;
    const int lane = tid & 63;
    const int wave = tid >> 6;
    const int n    = lane & 15;        // state index
    const int dl   = lane >> 4;        // 0..3
    const int d    = blockIdx.x * 16 + wave * 4 + dl;

    const float Anat = -__expf(A_log[(d << 4) + n]);
    const float dpd  = Dp[d];

    const float* xzrow = xz    + (size_t)b * Ls * DXZ;
    float*       xcrow = xconv + (size_t)b * Ls * DI;
    const float* bcrow = xdbl  + (size_t)b * Ls * DXD + DTR;

    float sdt[8], szv[8], sxv[8], sBv[8], sCv[8];
#pragma unroll
    for (int i = 0; i < 8; ++i) {
        sdt[i] = xzrow[(size_t)i * DXZ + d];
        szv[i] = xzrow[(size_t)i * DXZ + DI + d];
        sxv[i] = xcrow[(size_t)i * DI + d];
        sBv[i] = bcrow[(size_t)i * DXD + n];
        sCv[i] = bcrow[(size_t)i * DXD + DST + n];
    }

    float h = 0.0f;
    for (int t = 0; t < Ls; t += 8) {
#pragma unroll
        for (int i = 0; i < 8; ++i) {
            const float dtv = sdt[i], zv = szv[i], xv = sxv[i];
            const float Bn = sBv[i], Cn = sCv[i];
            const int tn = t + 8 + i;
            if (tn < Ls) {   // rolling 8-deep refill (uniform branch)
                sdt[i] = xzrow[(size_t)tn * DXZ + d];
                szv[i] = xzrow[(size_t)tn * DXZ + DI + d];
                sxv[i] = xcrow[(size_t)tn * DI + d];
                sBv[i] = bcrow[(size_t)tn * DXD + n];
                sCv[i] = bcrow[(size_t)tn * DXD + DST + n];
            }
            const float e = __expf(dtv * Anat);
            h = fmaf(e, h, dtv * xv * Bn);
            float p = h * Cn;
            p += __shfl_xor(p, 1);
            p += __shfl_xor(p, 2);
            p += __shfl_xor(p, 4);
            p += __shfl_xor(p, 8);
            const float yd = p + xv * dpd;
            if (n == 0)
                xcrow[(size_t)(t + i) * DI + d] = yd * (zv * sigmoidf_(zv));
        }
    }
}

// ---------------------------------------------------------------------------
extern "C" void kernel_launch(void* const* d_in, const int* in_sizes, int n_in,
                              void* d_out, int out_size, void* d_ws, size_t ws_size,
                              hipStream_t stream)
{
    const float* x      = (const float*)d_in[0];
    const float* W_in   = (const float*)d_in[1];
    const float* conv_w = (const float*)d_in[2];
    const float* conv_b = (const float*)d_in[3];
    const float* W_x    = (const float*)d_in[4];
    const float* W_dt   = (const float*)d_in[5];
    const float* b_dt   = (const float*)d_in[6];
    const float* A_log  = (const float*)d_in[7];
    const float* Dp     = (const float*)d_in[8];
    const float* W_out  = (const float*)d_in[9];
    float* out = (float*)d_out;

    const int M = Bb * Ls;  // 2048

    // workspace (proven 48.75 MB footprint — same as round 1):
    float* ws    = (float*)d_ws;
    float* xz    = ws;                        // [2048][4096] 32 MB
    float* xconv = xz    + (size_t)M * DXZ;   // [2048][2048] 16 MB
    float* xdbl  = xconv + (size_t)M * DI;    // [2048][96]  0.75 MB

    const dim3 blk(256);

    // 1) xz = x @ W_in^T  (bf16 MFMA, fp32 in/out)  M=2048 N=4096 K=1024
    gemm_bf16_f32in<<<dim3(DXZ / 128, M / 128), blk, 0, stream>>>(
        x, DM, W_in, DM, xz, DXZ, DM);

    // 2) depthwise causal conv + silu -> xconv (fp32); consumes xc half of xz
    conv_silu_kernel<<<dim3((M * DI) / 256), blk, 0, stream>>>(
        xz, conv_w, conv_b, xconv);

    // 3) x_dbl partials = xconv @ W_x^T  (fp32, split-K x8)  N=96, K=256/chunk
    //    partials land in the dead xc region: xz[m][kc*96 + j], cols 0..767
    gemm_nt<0><<<dim3(1, M / 128, 8), blk, 0, stream>>>(
        xconv, DI, W_x, DI, xz, DXZ, DXD, DI / 8, nullptr,
        DI / 8, DI / 8, DXD);
    reduce_xdbl_kernel<<<dim3((M * DXD + 255) / 256), blk, 0, stream>>>(
        xz, xdbl);

    // 4) dt = softplus(x_dbl[:, :64] @ W_dt^T + b_dt) -> xz cols 0..2047
    gemm_nt<1><<<dim3(DI / 128, M / 128), blk, 0, stream>>>(
        xdbl, DXD, W_dt, DTR, xz, DXZ, DI, DTR, b_dt, 0, 0, 0);

    // 5) parallel selective scan (+x*D, silu(z) gate) -> y* in-place (fp32)
    scan_kernel<<<dim3(DI / 16, Bb), blk, 0, stream>>>(
        xz, xconv, xdbl, A_log, Dp);

    // 6) out = y* @ W_out^T  (bf16 MFMA, fp32 in/out)  M=2048 N=1024 K=2048
    gemm_bf16_f32in<<<dim3(DM / 128, M / 128), blk, 0, stream>>>(
        xconv, DI, W_out, DI, out, DM, DI);
}

// Round 6
// 486.454 us; speedup vs baseline: 4.4854x; 1.9369x over previous
//
#include <hip/hip_runtime.h>
#include <hip/hip_bf16.h>
#include <math.h>

// Problem constants (B=2, L=1024, d_model=1024, d_inner=2048)
constexpr int Bb  = 2;
constexpr int Ls  = 1024;
constexpr int DM  = 1024;   // d_model
constexpr int DI  = 2048;   // d_inner
constexpr int DXZ = 4096;   // 2*d_inner
constexpr int DXD = 96;     // dt_rank + 2*d_state
constexpr int DTR = 64;     // dt_rank
constexpr int DST = 16;     // d_state
constexpr int NCH = 16;     // scan chunks
constexpr int CHL = 64;     // chunk length (NCH*CHL == Ls)

typedef __attribute__((ext_vector_type(8))) short bf16x8;
typedef __attribute__((ext_vector_type(4))) float f32x4;

__device__ __forceinline__ float sigmoidf_(float v) {
    return 1.0f / (1.0f + __expf(-v));
}

// pack two fp32 -> one dword of 2x bf16 (RTNE)
__device__ __forceinline__ int pk_bf16(float lo, float hi) {
    unsigned int ul = __float_as_uint(lo);
    ul += 0x7fffu + ((ul >> 16) & 1u);
    unsigned int uh = __float_as_uint(hi);
    uh += 0x7fffu + ((uh >> 16) & 1u);
    return (int)((ul >> 16) | (uh & 0xffff0000u));
}

// XOR-swizzled LDS chunk address: tile is [128 rows][4 chunks of 8 bf16].
__device__ __forceinline__ int swz(int row, int chunk) {
    return (((row << 2) + chunk) ^ (row & 7)) << 3;
}

// ---------------------------------------------------------------------------
// bf16 MFMA GEMM with fp32 inputs (in-register convert during staging):
// C[M,N] = A[M,K] @ W[N,K]^T, both fp32 row-major K-contig.
// 128x128 tile, 4 waves (2x2 of 64x64), BK=32. M%128==0, N%128==0, K%32==0.
// ---------------------------------------------------------------------------
__global__ __launch_bounds__(256) void gemm_bf16_f32in(
    const float* __restrict__ A, int lda,
    const float* __restrict__ W, int ldw,
    float* __restrict__ C, int ldc, int K)
{
    __shared__ __align__(16) unsigned short As[128 * 32];
    __shared__ __align__(16) unsigned short Ws[128 * 32];

    const int tid  = threadIdx.x;
    const int lane = tid & 63;
    const int wave = tid >> 6;
    const int bm = blockIdx.y * 128;
    const int bn = blockIdx.x * 128;

    const int srow = tid >> 1;
    const int cb   = (tid & 1) * 2;
    const float* Ag = A + (size_t)(bm + srow) * lda + cb * 8;
    const float* Wg = W + (size_t)(bn + srow) * ldw + cb * 8;
    const int ia0 = swz(srow, cb);
    const int ia1 = swz(srow, cb + 1);

    const int wr = (wave >> 1) * 64;
    const int wc = (wave & 1) * 64;
    const int fr = lane & 15;
    const int fq = lane >> 4;

    f32x4 acc[4][4];
#pragma unroll
    for (int m = 0; m < 4; ++m)
#pragma unroll
        for (int n = 0; n < 4; ++n) acc[m][n] = (f32x4){0.f, 0.f, 0.f, 0.f};

    for (int k0 = 0; k0 < K; k0 += 32) {
        const float4 a0 = *(const float4*)(Ag + k0);
        const float4 a1 = *(const float4*)(Ag + k0 + 4);
        const float4 a2 = *(const float4*)(Ag + k0 + 8);
        const float4 a3 = *(const float4*)(Ag + k0 + 12);
        const float4 w0 = *(const float4*)(Wg + k0);
        const float4 w1 = *(const float4*)(Wg + k0 + 4);
        const float4 w2 = *(const float4*)(Wg + k0 + 8);
        const float4 w3 = *(const float4*)(Wg + k0 + 12);

        __syncthreads();
        {
            const int4 pa0 = {pk_bf16(a0.x, a0.y), pk_bf16(a0.z, a0.w),
                              pk_bf16(a1.x, a1.y), pk_bf16(a1.z, a1.w)};
            const int4 pa1 = {pk_bf16(a2.x, a2.y), pk_bf16(a2.z, a2.w),
                              pk_bf16(a3.x, a3.y), pk_bf16(a3.z, a3.w)};
            const int4 pw0 = {pk_bf16(w0.x, w0.y), pk_bf16(w0.z, w0.w),
                              pk_bf16(w1.x, w1.y), pk_bf16(w1.z, w1.w)};
            const int4 pw1 = {pk_bf16(w2.x, w2.y), pk_bf16(w2.z, w2.w),
                              pk_bf16(w3.x, w3.y), pk_bf16(w3.z, w3.w)};
            *(int4*)(As + ia0) = pa0;
            *(int4*)(As + ia1) = pa1;
            *(int4*)(Ws + ia0) = pw0;
            *(int4*)(Ws + ia1) = pw1;
        }
        __syncthreads();

        bf16x8 af[4], bfv[4];
#pragma unroll
        for (int m = 0; m < 4; ++m)
            af[m] = *(const bf16x8*)(As + swz(wr + m * 16 + fr, fq));
#pragma unroll
        for (int n = 0; n < 4; ++n)
            bfv[n] = *(const bf16x8*)(Ws + swz(wc + n * 16 + fr, fq));
#pragma unroll
        for (int m = 0; m < 4; ++m)
#pragma unroll
            for (int n = 0; n < 4; ++n)
                acc[m][n] = __builtin_amdgcn_mfma_f32_16x16x32_bf16(
                    af[m], bfv[n], acc[m][n], 0, 0, 0);
    }

#pragma unroll
    for (int m = 0; m < 4; ++m)
#pragma unroll
        for (int n = 0; n < 4; ++n) {
            const int col = bn + wc + n * 16 + fr;
#pragma unroll
            for (int j = 0; j < 4; ++j) {
                const int row = bm + wr + m * 16 + fq * 4 + j;
                C[(size_t)row * ldc + col] = acc[m][n][j];
            }
        }
}

// ---------------------------------------------------------------------------
// Generic fp32 GEMM (small GEMMs): C[M,N] = A[M,K] @ W[N,K]^T.
// Split-K via blockIdx.z: A += z*za, W += z*zw, C += z*zc.
// EPI==1: softplus(C + bias[col]).
// ---------------------------------------------------------------------------
template <int EPI>
__global__ __launch_bounds__(256) void gemm_nt(
    const float* __restrict__ A, int lda,
    const float* __restrict__ W, int ldw,
    float* __restrict__ C, int ldc,
    int N, int K, const float* __restrict__ bias, int za, int zw, int zc)
{
    A += (size_t)blockIdx.z * za;
    W += (size_t)blockIdx.z * zw;
    C += (size_t)blockIdx.z * zc;

    __shared__ float Asl[16][132];
    __shared__ float Wsl[16][132];

    const int tid = threadIdx.x;
    const int tx = tid & 15;
    const int ty = tid >> 4;
    const int bm = blockIdx.y * 128;
    const int bn = blockIdx.x * 128;

    const int lr = tid >> 1;
    const int lk = (tid & 1) * 8;

    float acc[8][8];
#pragma unroll
    for (int i = 0; i < 8; ++i)
#pragma unroll
        for (int j = 0; j < 8; ++j) acc[i][j] = 0.0f;

    const float* Ap = A + (size_t)(bm + lr) * lda + lk;
    const float* Wp = W + (size_t)(bn + lr) * ldw + lk;
    const bool wok = (bn + lr) < N;
    const float4 f4z = make_float4(0.f, 0.f, 0.f, 0.f);

    for (int k0 = 0; k0 < K; k0 += 16) {
        const float4 av0 = *(const float4*)(Ap + k0);
        const float4 av1 = *(const float4*)(Ap + k0 + 4);
        const float4 wv0 = wok ? *(const float4*)(Wp + k0)     : f4z;
        const float4 wv1 = wok ? *(const float4*)(Wp + k0 + 4) : f4z;

        __syncthreads();
        Asl[lk + 0][lr] = av0.x; Asl[lk + 1][lr] = av0.y;
        Asl[lk + 2][lr] = av0.z; Asl[lk + 3][lr] = av0.w;
        Asl[lk + 4][lr] = av1.x; Asl[lk + 5][lr] = av1.y;
        Asl[lk + 6][lr] = av1.z; Asl[lk + 7][lr] = av1.w;
        Wsl[lk + 0][lr] = wv0.x; Wsl[lk + 1][lr] = wv0.y;
        Wsl[lk + 2][lr] = wv0.z; Wsl[lk + 3][lr] = wv0.w;
        Wsl[lk + 4][lr] = wv1.x; Wsl[lk + 5][lr] = wv1.y;
        Wsl[lk + 6][lr] = wv1.z; Wsl[lk + 7][lr] = wv1.w;
        __syncthreads();

#pragma unroll
        for (int k = 0; k < 16; ++k) {
            const float4 a0 = *(const float4*)&Asl[k][(ty << 2)];
            const float4 a1 = *(const float4*)&Asl[k][64 + (ty << 2)];
            const float4 b0 = *(const float4*)&Wsl[k][(tx << 2)];
            const float4 b1 = *(const float4*)&Wsl[k][64 + (tx << 2)];
            const float ar[8] = {a0.x, a0.y, a0.z, a0.w, a1.x, a1.y, a1.z, a1.w};
            const float br[8] = {b0.x, b0.y, b0.z, b0.w, b1.x, b1.y, b1.z, b1.w};
#pragma unroll
            for (int i = 0; i < 8; ++i)
#pragma unroll
                for (int j = 0; j < 8; ++j)
                    acc[i][j] = fmaf(ar[i], br[j], acc[i][j]);
        }
    }

#pragma unroll
    for (int i = 0; i < 8; ++i) {
        const int row = bm + ((i & 4) << 4) + (ty << 2) + (i & 3);
#pragma unroll
        for (int j = 0; j < 8; ++j) {
            const int col = bn + ((j & 4) << 4) + (tx << 2) + (j & 3);
            if (col < N) {
                float v = acc[i][j];
                if (EPI == 1) {
                    v += bias[col];
                    v = (v > 20.f) ? v : log1pf(__expf(v));
                }
                C[(size_t)row * ldc + col] = v;
            }
        }
    }
}

// ---------------------------------------------------------------------------
// Reduce split-K partials: xdbl[m][j] = sum_kc part[m*DXZ + kc*96 + j]
// ---------------------------------------------------------------------------
__global__ __launch_bounds__(256) void reduce_xdbl_kernel(
    const float* __restrict__ part, float* __restrict__ xdbl)
{
    const int idx = blockIdx.x * 256 + threadIdx.x;
    if (idx >= Bb * Ls * DXD) return;
    const int m = idx / DXD;
    const int j = idx - m * DXD;
    const float* p = part + (size_t)m * DXZ + j;
    float s = 0.0f;
#pragma unroll
    for (int kc = 0; kc < 8; ++kc) s += p[kc * DXD];
    xdbl[idx] = s;
}

// ---------------------------------------------------------------------------
// Depthwise causal conv (width 4) + bias + SiLU.
// ---------------------------------------------------------------------------
__global__ __launch_bounds__(256) void conv_silu_kernel(
    const float* __restrict__ xz,
    const float* __restrict__ conv_w,
    const float* __restrict__ conv_b,
    float* __restrict__ xconv)
{
    const int idx = blockIdx.x * 256 + threadIdx.x;
    const int d  = idx & (DI - 1);
    const int bl = idx >> 11;
    const int l  = bl & (Ls - 1);

    const float4 cw = *(const float4*)(conv_w + (d << 2));
    const float w[4] = {cw.x, cw.y, cw.z, cw.w};
    float acc = conv_b[d];
    const float* base = xz + (size_t)bl * DXZ + d;
#pragma unroll
    for (int j = 0; j < 4; ++j) {
        const int ll = l - 3 + j;
        if (ll >= 0) acc += base[(j - 3) * DXZ] * w[j];
    }
    xconv[idx] = acc * sigmoidf_(acc);
}

// ---------------------------------------------------------------------------
// Chunked scan pass 1: per (b,chunk,d,n) run CHL steps from h=0, emit
// chunk-end state hend and chunk decay product Dprod.
// Layout: idx = ((b*NCH+c)*DI+d)*DST+n  (n contiguous -> coalesced).
// ---------------------------------------------------------------------------
__global__ __launch_bounds__(256) void scan_pass1(
    const float* __restrict__ xz,      // cols 0..2047 = dt
    const float* __restrict__ xconv,   // x (silu conv)
    const float* __restrict__ xdbl,    // cols 64..79 = B
    const float* __restrict__ A_log,
    float* __restrict__ hend, float* __restrict__ Dprod)
{
    const int b    = blockIdx.z;
    const int c    = blockIdx.y;
    const int tid  = threadIdx.x;
    const int lane = tid & 63;
    const int wave = tid >> 6;
    const int n    = lane & 15;
    const int dl   = lane >> 4;
    const int d    = blockIdx.x * 16 + wave * 4 + dl;
    const int t0   = c * CHL;

    const float Anat = -__expf(A_log[(d << 4) + n]);

    const float* dtp = xz    + ((size_t)b * Ls + t0) * DXZ + d;
    const float* xp  = xconv + ((size_t)b * Ls + t0) * DI + d;
    const float* Bp  = xdbl  + ((size_t)b * Ls + t0) * DXD + DTR + n;

    float sdt[4], sxv[4], sBv[4];
#pragma unroll
    for (int i = 0; i < 4; ++i) {
        sdt[i] = dtp[(size_t)i * DXZ];
        sxv[i] = xp[(size_t)i * DI];
        sBv[i] = Bp[(size_t)i * DXD];
    }

    float h = 0.0f, dc = 1.0f;
    for (int t = 0; t < CHL; t += 4) {
#pragma unroll
        for (int i = 0; i < 4; ++i) {
            const float dtv = sdt[i], xv = sxv[i], Bn = sBv[i];
            const int tn = t + 4 + i;
            if (tn < CHL) {
                sdt[i] = dtp[(size_t)tn * DXZ];
                sxv[i] = xp[(size_t)tn * DI];
                sBv[i] = Bp[(size_t)tn * DXD];
            }
            const float e = __expf(dtv * Anat);
            dc *= e;
            h = fmaf(e, h, dtv * xv * Bn);
        }
    }

    const size_t idx = (((size_t)(b * NCH + c) * DI + d) << 4) + n;
    hend[idx]  = h;
    Dprod[idx] = dc;
}

// ---------------------------------------------------------------------------
// Combine: per (b,d,n) fold the NCH chunk summaries sequentially.
// Overwrites hend with the chunk-initial states h_init.
// ---------------------------------------------------------------------------
__global__ __launch_bounds__(256) void scan_combine(
    float* __restrict__ hend, const float* __restrict__ Dprod)
{
    const int idx = blockIdx.x * 256 + threadIdx.x;   // over Bb*DI*DST
    const int b   = idx >> 15;
    const int rem = idx & 32767;                      // d*16+n

    float carry = 0.0f;
#pragma unroll
    for (int c = 0; c < NCH; ++c) {
        const size_t off = (((size_t)(b * NCH + c)) << 15) + rem;
        const float hc = hend[off];
        const float Dc = Dprod[off];
        hend[off] = carry;                            // h_init for chunk c
        carry = fmaf(Dc, carry, hc);
    }
}

// ---------------------------------------------------------------------------
// Chunked scan pass 2: per (b,chunk,d,n) rerun CHL steps from h_init,
// reduce y over n via shfl_xor, fuse +x*D and silu(z) gate.
// Writes y* fp32 in-place over xconv.
// ---------------------------------------------------------------------------
__global__ __launch_bounds__(256) void scan_pass2(
    const float* __restrict__ xz,      // cols 0..2047 = dt, 2048.. = z
    float* __restrict__ xconv,         // in: x; out: y*
    const float* __restrict__ xdbl,    // cols 64..95 = B,C
    const float* __restrict__ A_log,
    const float* __restrict__ Dp,
    const float* __restrict__ hinit)
{
    const int b    = blockIdx.z;
    const int c    = blockIdx.y;
    const int tid  = threadIdx.x;
    const int lane = tid & 63;
    const int wave = tid >> 6;
    const int n    = lane & 15;
    const int dl   = lane >> 4;
    const int d    = blockIdx.x * 16 + wave * 4 + dl;
    const int t0   = c * CHL;

    const float Anat = -__expf(A_log[(d << 4) + n]);
    const float dpd  = Dp[d];

    const float* dtp = xz    + ((size_t)b * Ls + t0) * DXZ + d;
    const float* zp  = xz    + ((size_t)b * Ls + t0) * DXZ + DI + d;
    float*       xp  = xconv + ((size_t)b * Ls + t0) * DI + d;
    const float* Bp  = xdbl  + ((size_t)b * Ls + t0) * DXD + DTR + n;
    const float* Cp  = Bp + DST;

    float sdt[4], szv[4], sxv[4], sBv[4], sCv[4];
#pragma unroll
    for (int i = 0; i < 4; ++i) {
        sdt[i] = dtp[(size_t)i * DXZ];
        szv[i] = zp[(size_t)i * DXZ];
        sxv[i] = xp[(size_t)i * DI];
        sBv[i] = Bp[(size_t)i * DXD];
        sCv[i] = Cp[(size_t)i * DXD];
    }

    float h = hinit[(((size_t)(b * NCH + c) * DI + d) << 4) + n];

    for (int t = 0; t < CHL; t += 4) {
#pragma unroll
        for (int i = 0; i < 4; ++i) {
            const float dtv = sdt[i], zv = szv[i], xv = sxv[i];
            const float Bn = sBv[i], Cn = sCv[i];
            const int tn = t + 4 + i;
            if (tn < CHL) {
                sdt[i] = dtp[(size_t)tn * DXZ];
                szv[i] = zp[(size_t)tn * DXZ];
                sxv[i] = xp[(size_t)tn * DI];
                sBv[i] = Bp[(size_t)tn * DXD];
                sCv[i] = Cp[(size_t)tn * DXD];
            }
            const float e = __expf(dtv * Anat);
            h = fmaf(e, h, dtv * xv * Bn);
            float p = h * Cn;
            p += __shfl_xor(p, 1);
            p += __shfl_xor(p, 2);
            p += __shfl_xor(p, 4);
            p += __shfl_xor(p, 8);
            const float yd = p + xv * dpd;
            if (n == 0)
                xp[(size_t)(t + i) * DI] = yd * (zv * sigmoidf_(zv));
        }
    }
}

// ---------------------------------------------------------------------------
extern "C" void kernel_launch(void* const* d_in, const int* in_sizes, int n_in,
                              void* d_out, int out_size, void* d_ws, size_t ws_size,
                              hipStream_t stream)
{
    const float* x      = (const float*)d_in[0];
    const float* W_in   = (const float*)d_in[1];
    const float* conv_w = (const float*)d_in[2];
    const float* conv_b = (const float*)d_in[3];
    const float* W_x    = (const float*)d_in[4];
    const float* W_dt   = (const float*)d_in[5];
    const float* b_dt   = (const float*)d_in[6];
    const float* A_log  = (const float*)d_in[7];
    const float* Dp     = (const float*)d_in[8];
    const float* W_out  = (const float*)d_in[9];
    float* out = (float*)d_out;

    const int M = Bb * Ls;  // 2048

    // workspace (proven 48.75 MB footprint):
    float* ws    = (float*)d_ws;
    float* xz    = ws;                        // [2048][4096] 32 MB
    float* xconv = xz    + (size_t)M * DXZ;   // [2048][2048] 16 MB
    float* xdbl  = xconv + (size_t)M * DI;    // [2048][96]  0.75 MB

    // scan chunk summaries live in d_out (dead until the final GEMM):
    // hend/hinit = out[0 .. 1M), Dprod = out[1M .. 2M)  (exactly 8 MB)
    float* hend  = out;
    float* Dprod = out + (size_t)Bb * NCH * DI * DST;

    const dim3 blk(256);

    // 1) xz = x @ W_in^T  (bf16 MFMA, fp32 in/out)  M=2048 N=4096 K=1024
    gemm_bf16_f32in<<<dim3(DXZ / 128, M / 128), blk, 0, stream>>>(
        x, DM, W_in, DM, xz, DXZ, DM);

    // 2) depthwise causal conv + silu -> xconv (fp32)
    conv_silu_kernel<<<dim3((M * DI) / 256), blk, 0, stream>>>(
        xz, conv_w, conv_b, xconv);

    // 3) x_dbl partials = xconv @ W_x^T  (fp32, split-K x8), into dead xc cols
    gemm_nt<0><<<dim3(1, M / 128, 8), blk, 0, stream>>>(
        xconv, DI, W_x, DI, xz, DXZ, DXD, DI / 8, nullptr,
        DI / 8, DI / 8, DXD);
    reduce_xdbl_kernel<<<dim3((M * DXD + 255) / 256), blk, 0, stream>>>(
        xz, xdbl);

    // 4) dt = softplus(x_dbl[:, :64] @ W_dt^T + b_dt) -> xz cols 0..2047
    gemm_nt<1><<<dim3(DI / 128, M / 128), blk, 0, stream>>>(
        xdbl, DXD, W_dt, DTR, xz, DXZ, DI, DTR, b_dt, 0, 0, 0);

    // 5) chunked selective scan -> y* in-place over xconv
    scan_pass1<<<dim3(DI / 16, NCH, Bb), blk, 0, stream>>>(
        xz, xconv, xdbl, A_log, hend, Dprod);
    scan_combine<<<dim3((Bb * DI * DST) / 256), blk, 0, stream>>>(
        hend, Dprod);
    scan_pass2<<<dim3(DI / 16, NCH, Bb), blk, 0, stream>>>(
        xz, xconv, xdbl, A_log, Dp, hend);

    // 6) out = y* @ W_out^T  (bf16 MFMA, fp32 in/out)  M=2048 N=1024 K=2048
    gemm_bf16_f32in<<<dim3(DM / 128, M / 128), blk, 0, stream>>>(
        xconv, DI, W_out, DI, out, DM, DI);
}